// Round 30
// baseline (48.594 us; speedup 1.0000x reference)
//
#include <hip/hip_runtime.h>

#define KLEN 1024
#define HOP 512
#define NW 511
#define NB 4
#define NC 16
#define NBINS 513
#define NSAMP 262144
#define MAPN (NC * KLEN)

// ws layout (bytes): map float4[MAPN] @0 | hann float[1024] @262144
#define WS_HANN 262144

// XOR swizzle for the float2 FFT array: bank-pair-uniform for strides 1,4,64.
#define SWZ2(i) ((i) ^ (((i) >> 4) & 15))

// DIT butterfly: T = b*w; b = a - T; a = a + T
#define DITBF(ar,ai,br,bi,wr,wi) { float tr_=(br)*(wr)-(bi)*(wi), ti_=(br)*(wi)+(bi)*(wr); \
    (br)=(ar)-tr_; (bi)=(ai)-ti_; (ar)+=tr_; (ai)+=ti_; }
#define CMUL(xr,xi,yr,yi,or_,oi_) { (or_)=(xr)*(yr)-(xi)*(yi); (oi_)=(xr)*(yi)+(xi)*(yr); }

__global__ __launch_bounds__(256) void warpmap_kernel(
    const float* __restrict__ dlnf,
    float4* __restrict__ map, float* __restrict__ g_hann)
{
    const int c = blockIdx.x;
    const double TWO_PI = 6.283185307179586476925287;
    const double beta = 2.0 * (double)dlnf[c];
    const bool small = fabs(beta) < 1e-8;
    const double bs = small ? 1e-8 : beta;
    const double e2b = exp(2.0 * bs);
    const double t_mid = small ? 0.0 : (log(1.0 + 0.5 * (e2b - 1.0)) / bs - 1.0);

    for (int j = threadIdx.x; j < KLEN; j += 256) {
        double tau = 2.0 * (double)j / 1024.0 - 1.0;
        double ts, jac;
        if (small) { ts = tau; jac = 1.0; }
        else {
            ts = log(1.0 + (tau + 1.0) * 0.5 * (e2b - 1.0)) / bs - 1.0;
            jac = exp(-bs * (ts - t_mid));
        }
        double idxf = 512.0 * (ts + 1.0);
        int lo = (int)idxf;
        lo = lo < 0 ? 0 : (lo > 1022 ? 1022 : lo);
        map[c * KLEN + j] = make_float4(__int_as_float(lo),
                                        (float)(idxf - (double)lo),
                                        (float)jac, 0.0f);
    }
    if (c == 0) {
        for (int k = threadIdx.x; k < KLEN; k += 256)
            g_hann[k] = (float)(0.5 * (1.0 - cos(TWO_PI * (double)k / 1024.0)));
    }
}

// 4 in-register DIT stages on a 16-point group; u = W_1024^(j0 * 2^(6-s))
__device__ __forceinline__ void fft16_dit(float* vr, float* vi, float uc, float us)
{
    float u2r, u2i, u4r, u4i, u8r, u8i;
    CMUL(uc, us, uc, us, u2r, u2i);
    CMUL(u2r, u2i, u2r, u2i, u4r, u4i);
    CMUL(u4r, u4i, u4r, u4i, u8r, u8i);

    #pragma unroll
    for (int i = 0; i < 8; ++i)
        DITBF(vr[2*i], vi[2*i], vr[2*i+1], vi[2*i+1], u8r, u8i);

    #pragma unroll
    for (int i = 0; i < 4; ++i) {
        int t0 = (i >> 1) * 8 + (i & 1) * 4;   // 0,4,8,12
        DITBF(vr[t0],   vi[t0],   vr[t0+2], vi[t0+2], u4r, u4i);
        DITBF(vr[t0+1], vi[t0+1], vr[t0+3], vi[t0+3], u4i, -u4r);
    }

    {
        const float R2 = 0.70710678118654752f;
        float w1r, w1i, w3r, w3i;
        CMUL(u2r, u2i,  R2, -R2, w1r, w1i);
        CMUL(u2r, u2i, -R2, -R2, w3r, w3i);
        #pragma unroll
        for (int g = 0; g < 2; ++g) {
            int t0 = g * 8;
            DITBF(vr[t0],   vi[t0],   vr[t0+4], vi[t0+4], u2r, u2i);
            DITBF(vr[t0+1], vi[t0+1], vr[t0+5], vi[t0+5], w1r, w1i);
            DITBF(vr[t0+2], vi[t0+2], vr[t0+6], vi[t0+6], u2i, -u2r);
            DITBF(vr[t0+3], vi[t0+3], vr[t0+7], vi[t0+7], w3r, w3i);
        }
    }

    {
        constexpr float W16R[8] = { 1.0f, 0.92387953251f, 0.70710678119f, 0.38268343236f,
                                    0.0f,-0.38268343236f,-0.70710678119f,-0.92387953251f };
        constexpr float W16I[8] = { 0.0f,-0.38268343236f,-0.70710678119f,-0.92387953251f,
                                   -1.0f,-0.92387953251f,-0.70710678119f,-0.38268343236f };
        #pragma unroll
        for (int t = 0; t < 8; ++t) {
            float wr, wi;
            CMUL(uc, us, W16R[t], W16I[t], wr, wi);
            DITBF(vr[t], vi[t], vr[t+8], vi[t+8], wr, wi);
        }
    }
}

__global__ __launch_bounds__(256) void dechirp_fft16z_kernel(
    const float* __restrict__ x,
    const float4* __restrict__ map,
    const float* __restrict__ g_hann,
    float* __restrict__ out)
{
    __shared__ float2 wd2[KLEN];        // (v[k], v[k+1]) pairs, 8 KB
    __shared__ float2 zA[4][KLEN];      // packed (re, im) FFT arrays, 32 KB

    const int tid  = threadIdx.x;
    const int lane = tid & 63;
    const int wv   = tid >> 6;
    const int blin = blockIdx.x;            // (b*NW + w)*2 + half
    const int hlf  = blin & 1;
    const int w    = (blin >> 1) % NW;
    const int b    = blin / (2 * NW);
    const int q    = hlf * 4 + wv;          // chirp pair of this wave
    const int c0 = 2 * q, c1 = 2 * q + 1;

    // Build windowed pair table (one block barrier total)
    const float* xrow = x + (size_t)b * NSAMP + (size_t)w * HOP;
    {
        const int k4 = tid << 2;            // 0..1020
        float4 xv = *(const float4*)(xrow + k4);
        float4 hv = *(const float4*)(g_hann + k4);
        float v0 = xv.x * hv.x, v1 = xv.y * hv.y, v2 = xv.z * hv.z, v3 = xv.w * hv.w;
        int k5 = k4 + 4; if (k5 > 1023) k5 = 1023;
        float v4 = xrow[k5] * g_hann[k5];
        wd2[k4 + 0] = make_float2(v0, v1);
        wd2[k4 + 1] = make_float2(v1, v2);
        wd2[k4 + 2] = make_float2(v2, v3);
        wd2[k4 + 3] = make_float2(v3, v4);
    }
    __syncthreads();

    float2* z = zA[wv];
    const float4* m0 = map + c0 * KLEN;
    const float4* m1 = map + c1 * KLEN;

    // Fused resample + stages 0,1 (twiddles 1 and -i, exact).
    // Slots {4m..4m+3} (m = brev8(j0)) hold samples {j0, j0+512, j0+256, j0+768}.
    #pragma unroll
    for (int g = 0; g < 4; ++g) {
        const int j0 = lane + (g << 6);     // coalesced map loads
        float zr[4], zi[4];
        #pragma unroll
        for (int d = 0; d < 4; ++d) {
            constexpr int OFF[4] = {0, 512, 256, 768};
            int j = j0 + OFF[d];
            float4 a = m0[j];
            int a0 = __float_as_int(a.x);
            float2 p = wd2[a0];
            zr[d] = __builtin_fmaf(a.y, p.y - p.x, p.x) * a.z;
            float4 bq = m1[j];
            int a1 = __float_as_int(bq.x);
            float2 pp = wd2[a1];
            zi[d] = __builtin_fmaf(bq.y, pp.y - pp.x, pp.x) * bq.z;
        }
        float b0r = zr[0] + zr[1], b0i = zi[0] + zi[1];
        float b1r = zr[0] - zr[1], b1i = zi[0] - zi[1];
        float b2r = zr[2] + zr[3], b2i = zi[2] + zi[3];
        float b3r = zr[2] - zr[3], b3i = zi[2] - zi[3];
        const int base = ((int)(__brev((unsigned)j0) >> 24)) << 2;
        z[SWZ2(base + 0)] = make_float2(b0r + b2r, b0i + b2i);
        z[SWZ2(base + 2)] = make_float2(b0r - b2r, b0i - b2i);
        z[SWZ2(base + 1)] = make_float2(b1r + b3i, b1i - b3r);
        z[SWZ2(base + 3)] = make_float2(b1r - b3i, b1i + b3r);
    }
    __builtin_amdgcn_wave_barrier();

    // Pass A: radix-16 over stages 2..5. Group m=lane: slots base + 4t.
    {
        float vr[16], vi[16];
        const int j0 = lane & 3;
        const int base = ((lane >> 2) << 6) | j0;
        #pragma unroll
        for (int t = 0; t < 16; ++t) {
            float2 v = z[SWZ2(base + (t << 2))];
            vr[t] = v.x; vi[t] = v.y;
        }
        float uc, us;   // u = W^(16*j0)
        __sincosf((float)(j0 << 4) * (-6.283185307179586f / 1024.0f), &us, &uc);
        fft16_dit(vr, vi, uc, us);
        #pragma unroll
        for (int t = 0; t < 16; ++t)
            z[SWZ2(base + (t << 2))] = make_float2(vr[t], vi[t]);
    }
    __builtin_amdgcn_wave_barrier();

    // Pass B: radix-16 over stages 6..9. Group = lane: slots lane + 64t.
    float vr[16], vi[16];
    {
        #pragma unroll
        for (int t = 0; t < 16; ++t) {
            float2 v = z[SWZ2(lane + (t << 6))];
            vr[t] = v.x; vi[t] = v.y;
        }
        float uc, us;   // u = W^lane
        __sincosf((float)lane * (-6.283185307179586f / 1024.0f), &us, &uc);
        fft16_dit(vr, vi, uc, us);
        // vr/vi[t] = Z[lane + 64 t]  (natural order)
    }

    // Shfl unpack: partner of bin k=l+64t is lane 64-l, reg 15-t (lane 0: self, reg (16-t)&15)
    size_t obase0 = (((size_t)b * NW + w) * NC + c0) * NBINS;
    size_t obase1 = obase0 + NBINS;
    const int src = (64 - lane) & 63;
    #pragma unroll
    for (int t = 0; t < 8; ++t) {
        float pr = __shfl(vr[15 - t], src);
        float pi = __shfl(vi[15 - t], src);
        if (lane == 0) { pr = vr[(16 - t) & 15]; pi = vi[(16 - t) & 15]; }
        int k = lane + (t << 6);
        out[obase0 + k] = 0.5f * (vr[t] + pr);
        out[obase1 + k] = 0.5f * (vi[t] + pi);
    }
    if (lane == 0) {
        out[obase0 + 512] = vr[8];
        out[obase1 + 512] = vi[8];
    }
}

extern "C" void kernel_launch(void* const* d_in, const int* in_sizes, int n_in,
                              void* d_out, int out_size, void* d_ws, size_t ws_size,
                              hipStream_t stream) {
    const float* x = nullptr;
    const float* dlnf = nullptr;
    for (int i = 0; i < n_in; ++i) {
        if (in_sizes[i] == NB * NSAMP)      x = (const float*)d_in[i];
        else if (in_sizes[i] == NC)         dlnf = (const float*)d_in[i];
    }
    if (!x)    x    = (const float*)d_in[0];
    if (!dlnf) dlnf = (const float*)d_in[1];
    float* out = (float*)d_out;

    char* ws = (char*)d_ws;
    float4* map    = (float4*)ws;
    float*  g_hann = (float*)(ws + WS_HANN);

    warpmap_kernel<<<NC, 256, 0, stream>>>(dlnf, map, g_hann);

    const int nblocks = NB * NW * 2;  // 4088 blocks, 4 waves, 1 chirp-pair per wave
    dechirp_fft16z_kernel<<<nblocks, 256, 0, stream>>>(x, map, g_hann, out);
}

// Round 31
// 47.216 us; speedup vs baseline: 1.0292x; 1.0292x over previous
//
#include <hip/hip_runtime.h>

#define KLEN 1024
#define HOP 512
#define NW 511
#define NB 4
#define NC 16
#define NBINS 513
#define NSAMP 262144
#define MAPN (NC * KLEN)

// ws layout (bytes): map float4[MAPN] @0 | hann float[1024] @262144
#define WS_HANN 262144

// Bank-XOR swizzle: bijective in every 32-float segment; all strides <=2-way.
#define SWZ(i) (((i) & ~31) | (((i) ^ ((i) >> 5) ^ ((i) >> 10)) & 31))

// DIT butterfly: T = b*w; b = a - T; a = a + T
#define DITBF(ar,ai,br,bi,wr,wi) { float tr_=(br)*(wr)-(bi)*(wi), ti_=(br)*(wi)+(bi)*(wr); \
    (br)=(ar)-tr_; (bi)=(ai)-ti_; (ar)+=tr_; (ai)+=ti_; }
#define CMUL(xr,xi,yr,yi,or_,oi_) { (or_)=(xr)*(yr)-(xi)*(yi); (oi_)=(xr)*(yi)+(xi)*(yr); }

__global__ __launch_bounds__(256) void warpmap_kernel(
    const float* __restrict__ dlnf,
    float4* __restrict__ map, float* __restrict__ g_hann)
{
    const int c = blockIdx.x;
    const double TWO_PI = 6.283185307179586476925287;
    const double beta = 2.0 * (double)dlnf[c];
    const bool small = fabs(beta) < 1e-8;
    const double bs = small ? 1e-8 : beta;
    const double e2b = exp(2.0 * bs);
    const double t_mid = small ? 0.0 : (log(1.0 + 0.5 * (e2b - 1.0)) / bs - 1.0);

    for (int j = threadIdx.x; j < KLEN; j += 256) {
        double tau = 2.0 * (double)j / 1024.0 - 1.0;
        double ts, jac;
        if (small) { ts = tau; jac = 1.0; }
        else {
            ts = log(1.0 + (tau + 1.0) * 0.5 * (e2b - 1.0)) / bs - 1.0;
            jac = exp(-bs * (ts - t_mid));
        }
        double idxf = 512.0 * (ts + 1.0);
        int lo = (int)idxf;
        lo = lo < 0 ? 0 : (lo > 1022 ? 1022 : lo);
        map[c * KLEN + j] = make_float4(__int_as_float(lo),
                                        (float)(idxf - (double)lo),
                                        (float)jac, 0.0f);
    }
    if (c == 0) {
        for (int k = threadIdx.x; k < KLEN; k += 256)
            g_hann[k] = (float)(0.5 * (1.0 - cos(TWO_PI * (double)k / 1024.0)));
    }
}

// 4 in-register DIT stages on a 16-point group; u = W_1024^(j0 * 2^(6-s))
__device__ __forceinline__ void fft16_dit(float* vr, float* vi, float uc, float us)
{
    float u2r, u2i, u4r, u4i, u8r, u8i;
    CMUL(uc, us, uc, us, u2r, u2i);
    CMUL(u2r, u2i, u2r, u2i, u4r, u4i);
    CMUL(u4r, u4i, u4r, u4i, u8r, u8i);

    #pragma unroll
    for (int i = 0; i < 8; ++i)
        DITBF(vr[2*i], vi[2*i], vr[2*i+1], vi[2*i+1], u8r, u8i);

    #pragma unroll
    for (int i = 0; i < 4; ++i) {
        int t0 = (i >> 1) * 8 + (i & 1) * 4;   // 0,4,8,12
        DITBF(vr[t0],   vi[t0],   vr[t0+2], vi[t0+2], u4r, u4i);
        DITBF(vr[t0+1], vi[t0+1], vr[t0+3], vi[t0+3], u4i, -u4r);
    }

    {
        const float R2 = 0.70710678118654752f;
        float w1r, w1i, w3r, w3i;
        CMUL(u2r, u2i,  R2, -R2, w1r, w1i);
        CMUL(u2r, u2i, -R2, -R2, w3r, w3i);
        #pragma unroll
        for (int g = 0; g < 2; ++g) {
            int t0 = g * 8;
            DITBF(vr[t0],   vi[t0],   vr[t0+4], vi[t0+4], u2r, u2i);
            DITBF(vr[t0+1], vi[t0+1], vr[t0+5], vi[t0+5], w1r, w1i);
            DITBF(vr[t0+2], vi[t0+2], vr[t0+6], vi[t0+6], u2i, -u2r);
            DITBF(vr[t0+3], vi[t0+3], vr[t0+7], vi[t0+7], w3r, w3i);
        }
    }

    {
        constexpr float W16R[8] = { 1.0f, 0.92387953251f, 0.70710678119f, 0.38268343236f,
                                    0.0f,-0.38268343236f,-0.70710678119f,-0.92387953251f };
        constexpr float W16I[8] = { 0.0f,-0.38268343236f,-0.70710678119f,-0.92387953251f,
                                   -1.0f,-0.92387953251f,-0.70710678119f,-0.38268343236f };
        #pragma unroll
        for (int t = 0; t < 8; ++t) {
            float wr, wi;
            CMUL(uc, us, W16R[t], W16I[t], wr, wi);
            DITBF(vr[t], vi[t], vr[t+8], vi[t+8], wr, wi);
        }
    }
}

__global__ __launch_bounds__(256) void dechirp_fft16_kernel(
    const float* __restrict__ x,
    const float4* __restrict__ map,
    const float* __restrict__ g_hann,
    float* __restrict__ out)
{
    __shared__ float2 wd2[KLEN];                 // (v[k], v[k+1]) pairs, 8 KB
    __shared__ float reA[4][KLEN], imA[4][KLEN]; // 32 KB

    const int tid  = threadIdx.x;
    const int lane = tid & 63;
    const int wv   = tid >> 6;
    const int blin = blockIdx.x;            // (b*NW + w)*2 + half
    const int hlf  = blin & 1;
    const int w    = (blin >> 1) % NW;
    const int b    = blin / (2 * NW);
    const int q    = hlf * 4 + wv;          // chirp pair of this wave
    const int c0 = 2 * q, c1 = 2 * q + 1;

    // Build windowed pair table (one block barrier total)
    const float* xrow = x + (size_t)b * NSAMP + (size_t)w * HOP;
    {
        const int k4 = tid << 2;            // 0..1020
        float4 xv = *(const float4*)(xrow + k4);
        float4 hv = *(const float4*)(g_hann + k4);
        float v0 = xv.x * hv.x, v1 = xv.y * hv.y, v2 = xv.z * hv.z, v3 = xv.w * hv.w;
        int k5 = k4 + 4; if (k5 > 1023) k5 = 1023;
        float v4 = xrow[k5] * g_hann[k5];
        wd2[k4 + 0] = make_float2(v0, v1);
        wd2[k4 + 1] = make_float2(v1, v2);
        wd2[k4 + 2] = make_float2(v2, v3);
        wd2[k4 + 3] = make_float2(v3, v4);
    }
    __syncthreads();

    float* re = reA[wv];
    float* im = imA[wv];
    const float4* m0 = map + c0 * KLEN;
    const float4* m1 = map + c1 * KLEN;

    // Fused resample + stages 0,1 (twiddles 1 and -i, exact).
    // Slots {4m..4m+3} (m = brev8(j0)) hold samples {j0, j0+512, j0+256, j0+768}.
    #pragma unroll
    for (int g = 0; g < 4; ++g) {
        const int j0 = lane + (g << 6);     // coalesced map loads
        float zr[4], zi[4];
        #pragma unroll
        for (int d = 0; d < 4; ++d) {
            constexpr int OFF[4] = {0, 512, 256, 768};
            int j = j0 + OFF[d];
            float4 a = m0[j];
            int a0 = __float_as_int(a.x);
            float2 p = wd2[a0];
            zr[d] = (p.x * (1.0f - a.y) + p.y * a.y) * a.z;
            float4 bq = m1[j];
            int a1 = __float_as_int(bq.x);
            float2 pp = wd2[a1];
            zi[d] = (pp.x * (1.0f - bq.y) + pp.y * bq.y) * bq.z;
        }
        float b0r = zr[0] + zr[1], b0i = zi[0] + zi[1];
        float b1r = zr[0] - zr[1], b1i = zi[0] - zi[1];
        float b2r = zr[2] + zr[3], b2i = zi[2] + zi[3];
        float b3r = zr[2] - zr[3], b3i = zi[2] - zi[3];
        const int base = ((int)(__brev((unsigned)j0) >> 24)) << 2;
        re[SWZ(base + 0)] = b0r + b2r;  im[SWZ(base + 0)] = b0i + b2i;
        re[SWZ(base + 2)] = b0r - b2r;  im[SWZ(base + 2)] = b0i - b2i;
        re[SWZ(base + 1)] = b1r + b3i;  im[SWZ(base + 1)] = b1i - b3r;
        re[SWZ(base + 3)] = b1r - b3i;  im[SWZ(base + 3)] = b1i + b3r;
    }
    __builtin_amdgcn_wave_barrier();

    // Pass A: radix-16 over stages 2..5. Group m=lane: slots base + 4t.
    {
        float vr[16], vi[16];
        const int j0 = lane & 3;
        const int base = ((lane >> 2) << 6) | j0;
        #pragma unroll
        for (int t = 0; t < 16; ++t) {
            int idx = SWZ(base + (t << 2));
            vr[t] = re[idx]; vi[t] = im[idx];
        }
        float uc, us;   // u = W^(16*j0)
        __sincosf((float)(j0 << 4) * (-6.283185307179586f / 1024.0f), &us, &uc);
        fft16_dit(vr, vi, uc, us);
        #pragma unroll
        for (int t = 0; t < 16; ++t) {
            int idx = SWZ(base + (t << 2));
            re[idx] = vr[t]; im[idx] = vi[t];
        }
    }
    __builtin_amdgcn_wave_barrier();

    // Pass B: radix-16 over stages 6..9. Group = lane: slots lane + 64t.
    float vr[16], vi[16];
    {
        #pragma unroll
        for (int t = 0; t < 16; ++t) {
            int idx = SWZ(lane + (t << 6));
            vr[t] = re[idx]; vi[t] = im[idx];
        }
        float uc, us;   // u = W^lane
        __sincosf((float)lane * (-6.283185307179586f / 1024.0f), &us, &uc);
        fft16_dit(vr, vi, uc, us);
        // vr/vi[t] = Z[lane + 64 t]  (natural order)
    }

    // Shfl unpack: partner of bin k=l+64t is lane 64-l, reg 15-t (lane 0: self, reg (16-t)&15)
    size_t obase0 = (((size_t)b * NW + w) * NC + c0) * NBINS;
    size_t obase1 = obase0 + NBINS;
    const int src = (64 - lane) & 63;
    #pragma unroll
    for (int t = 0; t < 8; ++t) {
        float pr = __shfl(vr[15 - t], src);
        float pi = __shfl(vi[15 - t], src);
        if (lane == 0) { pr = vr[(16 - t) & 15]; pi = vi[(16 - t) & 15]; }
        int k = lane + (t << 6);
        out[obase0 + k] = 0.5f * (vr[t] + pr);
        out[obase1 + k] = 0.5f * (vi[t] + pi);
    }
    if (lane == 0) {
        out[obase0 + 512] = vr[8];
        out[obase1 + 512] = vi[8];
    }
}

extern "C" void kernel_launch(void* const* d_in, const int* in_sizes, int n_in,
                              void* d_out, int out_size, void* d_ws, size_t ws_size,
                              hipStream_t stream) {
    const float* x = nullptr;
    const float* dlnf = nullptr;
    for (int i = 0; i < n_in; ++i) {
        if (in_sizes[i] == NB * NSAMP)      x = (const float*)d_in[i];
        else if (in_sizes[i] == NC)         dlnf = (const float*)d_in[i];
    }
    if (!x)    x    = (const float*)d_in[0];
    if (!dlnf) dlnf = (const float*)d_in[1];
    float* out = (float*)d_out;

    char* ws = (char*)d_ws;
    float4* map    = (float4*)ws;
    float*  g_hann = (float*)(ws + WS_HANN);

    warpmap_kernel<<<NC, 256, 0, stream>>>(dlnf, map, g_hann);

    const int nblocks = NB * NW * 2;  // 4088 blocks, 4 waves, 1 chirp-pair per wave
    dechirp_fft16_kernel<<<nblocks, 256, 0, stream>>>(x, map, g_hann, out);
}